// Round 6
// baseline (495.037 us; speedup 1.0000x reference)
//
#include <hip/hip_runtime.h>
#include <stdint.h>

#define T_LEN 512
#define IN0   9
#define H     56
#define BG    8
#define NW    14
#define NTH   (NW * 64)        // 896 threads: waves 0-6 = L0 group, 7-13 = L1 group
#define NBLK  256

typedef __attribute__((ext_vector_type(8))) short bfrag;   // 8 bf16
typedef __attribute__((ext_vector_type(4))) float ffrag;   // 4 fp32

#define MFMA(a,b,c) __builtin_amdgcn_mfma_f32_16x16x32_bf16((a),(b),(c),0,0,0)

__device__ __forceinline__ uint32_t bf16hi(float x) {
  uint32_t u = __float_as_uint(x);
  return (u + 0x7FFFu + ((u >> 16) & 1u)) & 0xFFFF0000u;
}
// RNE both halves (weights, init-time only)
__device__ __forceinline__ void split_bf16(float x, short& hs, short& ls) {
  uint32_t hb = bf16hi(x);
  float lf = x - __uint_as_float(hb);
  hs = (short)(hb >> 16);
  ls = (short)(bf16hi(lf) >> 16);
}
// RNE hi, truncated lo (loop-time)
__device__ __forceinline__ void split_bf16t(float x, short& hs, short& ls) {
  uint32_t hb = bf16hi(x);
  float lf = x - __uint_as_float(hb);
  hs = (short)(hb >> 16);
  ls = (short)(__float_as_uint(lf) >> 16);
}
// returns lane(v ^ 8), via DPP row_ror:8 (xor-8 == ror-8 within 16-lane rows)
__device__ __forceinline__ float dpp8(float v) {
  return __int_as_float(__builtin_amdgcn_update_dpp(0, __float_as_int(v), 0x128, 0xF, 0xF, true));
}
__device__ __forceinline__ float rcp_f(float v)  { return __builtin_amdgcn_rcpf(v); }
__device__ __forceinline__ float sigm_f(float v) { return rcp_f(1.0f + __expf(-v)); }
__device__ __forceinline__ float tanh_f(float v) { return 1.0f - 2.0f * rcp_f(1.0f + __expf(2.0f * v)); }

// cumulative per-step flag target: step s completed by all 7 group waves
// when flg[slot s&7] >= 7*((s>>3)+1). s<0 -> 0 (trivially satisfied).
__device__ __forceinline__ int ftgt(int s) { return (s < 0) ? 0 : 7 * ((s >> 3) + 1); }

__device__ __forceinline__ void wait_flag(const int* f, int tgt) {
  if (tgt <= 0) return;
  const volatile int* vf = (const volatile int*)f;
  if (*vf < tgt) {
    int guard = 1 << 13;                 // bailout: wrong answer beats a hang
    do { __builtin_amdgcn_s_sleep(2); } while (*vf < tgt && --guard);
  }
  asm volatile("" ::: "memory");         // compiler fence: no hoisting reads above
}

__global__ __launch_bounds__(NTH, 4)
void lstm_mfma13(const float* __restrict__ x,
                 const float* __restrict__ w_ih0, const float* __restrict__ w_hh0,
                 const float* __restrict__ b_ih0, const float* __restrict__ b_hh0,
                 const float* __restrict__ w_ih1, const float* __restrict__ w_hh1,
                 const float* __restrict__ b_ih1, const float* __restrict__ b_hh1,
                 const float* __restrict__ fc1_w, const float* __restrict__ fc1_b,
                 const float* __restrict__ fc2_w, const float* __restrict__ fc2_b,
                 float* __restrict__ out)
{
  // BARRIER-FREE producer/consumer structure.
  // Waves 0-6 (L0 group) compute layer-0 steps t=0..511; waves 7-13 (L1 group)
  // compute layer-1 steps s (lagging L0 by ~1). Each wave owns TWO 16-row
  // stripes (A = 2wg, B = 2wg+1); the column-half (c16<8 / >=8) selects which
  // stripe a lane's act item comes from (replaces the old lay split -> same
  // per-lane act count, same 8 MFMA/wave, L0 waves only 2 ds_reads).
  // Sync via per-step cumulative LDS counters (ds_add after lgkmcnt(0)):
  //   L0(t) waits C0[t-1], C1[t-2];  L1(s) waits C0[s], C1[s-1].
  // These cover all reads AND all 2-slot ring overwrites; wait-graph acyclic.
  // h rings: h0 -> regions 0,1 (slot t&1); h1 -> regions 2,3 (slot s&1).
  // Numerics verbatim the 428us/r3 kernel (bit-identical path).
  __shared__ __align__(16) short hbufS[4 * 1024];     //  8 KiB: h0/h1 2-slot rings
  __shared__ __align__(16) short xfS[T_LEN * 128];    // 128 KiB: x fragments
  __shared__ __align__(16) float x8S[T_LEN * BG];     //  16 KiB: x[8]
  __shared__ float sF[BG * H];
  __shared__ float sY[BG * 28];
  __shared__ int   flg[16];                           // [0..7]=C0, [8..15]=C1

  const int tid  = threadIdx.x;
  const int lane = tid & 63;
  const int w    = tid >> 6;
  const int c16  = lane & 15;
  const int quad = lane >> 4;

  const int  grp  = (w >= 7);            // 0 = L0 group, 1 = L1 group
  const int  wg   = grp ? (w - 7) : w;   // 0..6 within group
  const bool selB = (c16 >= 8);          // lane's act item: stripe A or B
  const int  b    = lane & 7;
  const int  sA   = 2 * wg, sB = 2 * wg + 1;
  const int  j_sel = 4 * (selB ? sB : sA) + quad;     // this lane's h element j

  for (int i = tid; i < 2048; i += NTH) ((int*)hbufS)[i] = 0;
  if (tid < 16) flg[tid] = 0;

  // h store offset within a 1024-short region (fragment-linear [64 rows][16 cols])
  const int kk   = j_sel & 31;
  const int offE = (j_sel >> 5) * 512 + ((kk >> 3) * 16 + b) * 8 + (kk & 7);

  // ---- x prefill: all 512 timesteps into LDS (fragment layout + x8 plane) ----
  for (int item = tid; item < T_LEN * BG; item += NTH) {
    const int t  = item & (T_LEN - 1);
    const int bb = item >> 9;
    const float* xr = x + ((size_t)(blockIdx.x * BG + bb) * T_LEN + t) * IN0;
    union { short s[8]; bfrag v; } hi, lo;
    #pragma unroll
    for (int q = 0; q < 8; ++q) split_bf16t(xr[q], hi.s[q], lo.s[q]);
    *(bfrag*)((char*)xfS + (size_t)t * 256 + bb * 16)       = hi.v;
    *(bfrag*)((char*)xfS + (size_t)t * 256 + (bb + 8) * 16) = lo.v;
    x8S[t * 8 + bb] = xr[8];
  }

  const char* const ldsb = (const char*)hbufS;
  const char* const xfb  = (const char*)xfS;
  const ffrag zerof = { 0.f, 0.f, 0.f, 0.f };
  const int incU1 = (quad == 3) ? 512 : 0;
  float cst = 0.f;

  __syncthreads();                       // zeros + x prefill + flags visible

#define SIGNAL(IDX8, STEP)                                                      \
  asm volatile("s_waitcnt lgkmcnt(0)" ::: "memory");                            \
  if (lane == 0) atomicAdd(&flg[(IDX8) + ((STEP) & 7)], 1);

  if (!grp) {
    // ================= L0 group =================
    bfrag B0hA[2], B0lA[2], B0hB[2], B0lB[2];
#define LOADW0(SUF, SIDX)                                                       \
    {                                                                           \
      const int np_ = 16 * (SIDX) + c16;                                        \
      const int wrow_ = (np_ & 3) * H + (np_ >> 2);                             \
      _Pragma("unroll")                                                         \
      for (int s = 0; s < 2; ++s) {                                             \
        union { short sh[8]; bfrag v; } ah, al;                                 \
        _Pragma("unroll")                                                       \
        for (int jj = 0; jj < 8; ++jj) {                                        \
          const int k = 32 * s + quad * 8 + jj;                                 \
          const float w0 = (k < H) ? w_hh0[wrow_ * H + k]                       \
                                   : w_ih0[wrow_ * IN0 + (k - 56)];             \
          split_bf16(w0, ah.sh[jj], al.sh[jj]);                                 \
        }                                                                       \
        B0h##SUF[s] = ah.v; B0l##SUF[s] = al.v;                                 \
      }                                                                         \
    }
    LOADW0(A, sA)
    LOADW0(B, sB)
#undef LOADW0

    ffrag bias0A, bias0B;
    #pragma unroll
    for (int r = 0; r < 4; ++r) {
      const int jA = 4 * sA + quad, jB = 4 * sB + quad;
      bias0A[r] = (c16 < 8) ? (b_ih0[r * H + jA] + b_hh0[r * H + jA]) : 0.0f;
      bias0B[r] = (c16 < 8) ? (b_ih0[r * H + jB] + b_hh0[r * H + jB]) : 0.0f;
    }
    float wx8s[4];
    #pragma unroll
    for (int r = 0; r < 4; ++r)
      wx8s[r] = w_ih0[(r * H + j_sel) * IN0 + 8];

    // read slot = (t-1)&1 ; P = t&1
    const char* const pU0_0 = ldsb + 2048 + lane * 16;
    const char* const pU0_1 = ldsb +        lane * 16;
    const char* pU1_0 = (quad == 3) ? (xfb +       c16 * 16) : (ldsb + 3072 + lane * 16);
    const char* pU1_1 = (quad == 3) ? (xfb + 256 + c16 * 16) : (ldsb + 1024 + lane * 16);
    const char* px8_0 = (const char*)x8S +      b * 4;
    const char* px8_1 = (const char*)x8S + 32 + b * 4;
    short* const hw_0 = hbufS +        offE;   // write slot 0
    short* const hw_1 = hbufS + 1024 + offE;   // write slot 1

#define STEP0(P, TT)                                                            \
    {                                                                           \
      const float x8v = *(const float*)px8_##P;                                 \
      wait_flag(&flg[((TT) - 1) & 7], ftgt((TT) - 1));                          \
      wait_flag(&flg[8 + (((TT) - 2) & 7)], ftgt((TT) - 2));                    \
      const bfrag U0 = *(const bfrag*)pU0_##P;                                  \
      const bfrag U1 = *(const bfrag*)pU1_##P;                                  \
      __builtin_amdgcn_s_setprio(1);                                            \
      ffrag aA = MFMA(B0hA[0], U0, bias0A);                                     \
      ffrag bA = MFMA(B0lA[0], U0, zerof);                                      \
      aA = MFMA(B0hA[1], U1, aA);                                               \
      bA = MFMA(B0lA[1], U1, bA);                                               \
      ffrag aB = MFMA(B0hB[0], U0, bias0B);                                     \
      ffrag bB = MFMA(B0lB[0], U0, zerof);                                      \
      aB = MFMA(B0hB[1], U1, aB);                                               \
      bB = MFMA(B0lB[1], U1, bB);                                               \
      __builtin_amdgcn_s_setprio(0);                                            \
      float sv[4];                                                              \
      _Pragma("unroll")                                                         \
      for (int r = 0; r < 4; ++r) {                                             \
        const float da = aA[r] + bA[r];                                         \
        const float db = aB[r] + bB[r];                                         \
        const float uu = selB ? db : da;                                        \
        const float vv = selB ? da : db;                                        \
        sv[r] = uu + dpp8(vv);                                                  \
      }                                                                         \
      const float gi = fmaf(wx8s[0], x8v, sv[0]);                               \
      const float gf = fmaf(wx8s[1], x8v, sv[1]);                               \
      const float gg = fmaf(wx8s[2], x8v, sv[2]);                               \
      const float go = fmaf(wx8s[3], x8v, sv[3]);                               \
      const float iv = sigm_f(gi), fv = sigm_f(gf);                             \
      const float gv = tanh_f(gg), ov = sigm_f(go);                             \
      cst = fmaf(fv, cst, iv * gv);                                             \
      const float hv = ov * tanh_f(cst);                                        \
      short hs, hl; split_bf16t(hv, hs, hl);                                    \
      hw_##P[0] = hs; hw_##P[64] = hl;                                          \
      SIGNAL(0, TT)                                                             \
    }

    for (int t = 0; t < T_LEN; t += 2) {
      STEP0(0, t)
      STEP0(1, t + 1)
      pU1_0 += incU1; pU1_1 += incU1;
      px8_0 += 64;    px8_1 += 64;
    }
#undef STEP0
  } else {
    // ================= L1 group =================
    bfrag BuhA[2], BhhA[2], BuhB[2], BhhB[2];
#define LOADW1(SUF, SIDX)                                                       \
    {                                                                           \
      const int np_ = 16 * (SIDX) + c16;                                        \
      const int wrow_ = (np_ & 3) * H + (np_ >> 2);                             \
      _Pragma("unroll")                                                         \
      for (int s = 0; s < 2; ++s) {                                             \
        union { short sh[8]; bfrag v; } au, ah;                                 \
        _Pragma("unroll")                                                       \
        for (int jj = 0; jj < 8; ++jj) {                                        \
          const int k = 32 * s + quad * 8 + jj;                                 \
          const float wu = (k < H) ? w_ih1[wrow_ * H + k] : 0.0f;               \
          const float wh = (k < H) ? w_hh1[wrow_ * H + k] : 0.0f;               \
          short dum;                                                            \
          split_bf16(wu, au.sh[jj], dum);   /* RNE hi only */                   \
          split_bf16(wh, ah.sh[jj], dum);                                       \
        }                                                                       \
        Buh##SUF[s] = au.v; Bhh##SUF[s] = ah.v;                                 \
      }                                                                         \
    }
    LOADW1(A, sA)
    LOADW1(B, sB)
#undef LOADW1

    ffrag bias1A, bias1B;
    #pragma unroll
    for (int r = 0; r < 4; ++r) {
      const int jA = 4 * sA + quad, jB = 4 * sB + quad;
      bias1A[r] = (c16 < 8) ? (b_ih1[r * H + jA] + b_hh1[r * H + jA]) : 0.0f;
      bias1B[r] = (c16 < 8) ? (b_ih1[r * H + jB] + b_hh1[r * H + jB]) : 0.0f;
    }

    // U slot = s&1 (h0(s)); H slot = (s-1)&1 (h1(s-1)); P = s&1
    const char* const qU0_0 = ldsb +        lane * 16;
    const char* const qU0_1 = ldsb + 2048 + lane * 16;
    const char* qU1_0 = (quad == 3) ? (xfb +       c16 * 16) : (ldsb + 1024 + lane * 16);
    const char* qU1_1 = (quad == 3) ? (xfb + 256 + c16 * 16) : (ldsb + 3072 + lane * 16);
    const char* const qH0_0 = ldsb + 4096 + 2048 + lane * 16;   // h1 slot 1
    const char* const qH1_0 = qH0_0 + 1024;
    const char* const qH0_1 = ldsb + 4096 +        lane * 16;   // h1 slot 0
    const char* const qH1_1 = qH0_1 + 1024;
    short* const qw_0 = hbufS + 2 * 1024 + offE;
    short* const qw_1 = hbufS + 3 * 1024 + offE;

#define STEP1(P, SS, LAST)                                                      \
    {                                                                           \
      wait_flag(&flg[(SS) & 7], ftgt(SS));                                      \
      wait_flag(&flg[8 + (((SS) - 1) & 7)], ftgt((SS) - 1));                    \
      const bfrag U0 = *(const bfrag*)qU0_##P;                                  \
      const bfrag U1 = *(const bfrag*)qU1_##P;                                  \
      const bfrag H0 = *(const bfrag*)qH0_##P;                                  \
      const bfrag H1 = *(const bfrag*)qH1_##P;                                  \
      __builtin_amdgcn_s_setprio(1);                                            \
      ffrag hA = MFMA(BhhA[0], H0, bias1A);                                     \
      hA = MFMA(BhhA[1], H1, hA);                                               \
      hA = MFMA(BuhA[0], U0, hA);                                               \
      hA = MFMA(BuhA[1], U1, hA);                                               \
      ffrag hBv = MFMA(BhhB[0], H0, bias1B);                                    \
      hBv = MFMA(BhhB[1], H1, hBv);                                             \
      hBv = MFMA(BuhB[0], U0, hBv);                                             \
      hBv = MFMA(BuhB[1], U1, hBv);                                             \
      __builtin_amdgcn_s_setprio(0);                                            \
      float sv[4];                                                              \
      _Pragma("unroll")                                                         \
      for (int r = 0; r < 4; ++r) {                                             \
        const float uu = selB ? hBv[r] : hA[r];                                 \
        const float vv = selB ? hA[r] : hBv[r];                                 \
        sv[r] = uu + dpp8(vv);                                                  \
      }                                                                         \
      const float iv = sigm_f(sv[0]), fv = sigm_f(sv[1]);                       \
      const float gv = tanh_f(sv[2]), ov = sigm_f(sv[3]);                       \
      cst = fmaf(fv, cst, iv * gv);                                             \
      const float hv = ov * tanh_f(cst);                                        \
      if (!(LAST)) {                                                            \
        short hs, hl; split_bf16t(hv, hs, hl);                                  \
        qw_##P[0] = hs; qw_##P[64] = hl;                                        \
        SIGNAL(8, SS)                                                           \
      } else {                                                                  \
        sF[b * H + j_sel] = hv;                                                 \
      }                                                                         \
    }

    for (int s = 0; s < T_LEN - 2; s += 2) {
      STEP1(0, s, 0)
      STEP1(1, s + 1, 0)
      qU1_0 += incU1; qU1_1 += incU1;
    }
    STEP1(0, T_LEN - 2, 0)
    STEP1(1, T_LEN - 1, 1)
#undef STEP1
  }
#undef SIGNAL

  __syncthreads();

  // ---- FC head on final h1 ----
  if (tid < 28 * BG) {
    const int m  = tid >> 3;
    const int bb = tid & 7;
    float acc = fc1_b[m];
    const float4* w4 = (const float4*)(fc1_w + m * H);
    const float4* h4 = (const float4*)(sF + bb * H);
    #pragma unroll
    for (int qq = 0; qq < H / 4; ++qq) {
      const float4 wv4 = w4[qq], hv4 = h4[qq];
      acc = fmaf(wv4.x, hv4.x, acc);
      acc = fmaf(wv4.y, hv4.y, acc);
      acc = fmaf(wv4.z, hv4.z, acc);
      acc = fmaf(wv4.w, hv4.w, acc);
    }
    sY[bb * 28 + m] = fmaxf(acc, 0.0f);
  }
  __syncthreads();
  if (tid < BG) {
    float acc = fc2_b[0];
    #pragma unroll
    for (int m = 0; m < 28; ++m)
      acc = fmaf(fc2_w[m], sY[tid * 28 + m], acc);
    out[blockIdx.x * BG + tid] = acc;
  }
}

extern "C" void kernel_launch(void* const* d_in, const int* in_sizes, int n_in,
                              void* d_out, int out_size, void* d_ws, size_t ws_size,
                              hipStream_t stream)
{
  const float* x     = (const float*)d_in[0];
  const float* w_ih0 = (const float*)d_in[1];
  const float* w_hh0 = (const float*)d_in[2];
  const float* b_ih0 = (const float*)d_in[3];
  const float* b_hh0 = (const float*)d_in[4];
  const float* w_ih1 = (const float*)d_in[5];
  const float* w_hh1 = (const float*)d_in[6];
  const float* b_ih1 = (const float*)d_in[7];
  const float* b_hh1 = (const float*)d_in[8];
  const float* fc1_w = (const float*)d_in[9];
  const float* fc1_b = (const float*)d_in[10];
  const float* fc2_w = (const float*)d_in[11];
  const float* fc2_b = (const float*)d_in[12];
  float* out = (float*)d_out;

  lstm_mfma13<<<NBLK, NTH, 0, stream>>>(
      x, w_ih0, w_hh0, b_ih0, b_hh0, w_ih1, w_hh1, b_ih1, b_hh1,
      fc1_w, fc1_b, fc2_w, fc2_b, out);
}

// Round 7
// 479.275 us; speedup vs baseline: 1.0329x; 1.0329x over previous
//
#include <hip/hip_runtime.h>
#include <stdint.h>

#define T_LEN 512
#define IN0   9
#define H     56
#define BG    8
#define NW    14
#define NTH   (NW * 64)        // 896 threads: waves 0-6 = L0 group, 7-13 = L1 group
#define NBLK  256

typedef __attribute__((ext_vector_type(8))) short bfrag;   // 8 bf16
typedef __attribute__((ext_vector_type(4))) float ffrag;   // 4 fp32

#define MFMA(a,b,c) __builtin_amdgcn_mfma_f32_16x16x32_bf16((a),(b),(c),0,0,0)

__device__ __forceinline__ uint32_t bf16hi(float x) {
  uint32_t u = __float_as_uint(x);
  return (u + 0x7FFFu + ((u >> 16) & 1u)) & 0xFFFF0000u;
}
// RNE both halves (weights, init-time only)
__device__ __forceinline__ void split_bf16(float x, short& hs, short& ls) {
  uint32_t hb = bf16hi(x);
  float lf = x - __uint_as_float(hb);
  hs = (short)(hb >> 16);
  ls = (short)(bf16hi(lf) >> 16);
}
// RNE hi, truncated lo (loop-time)
__device__ __forceinline__ void split_bf16t(float x, short& hs, short& ls) {
  uint32_t hb = bf16hi(x);
  float lf = x - __uint_as_float(hb);
  hs = (short)(hb >> 16);
  ls = (short)(__float_as_uint(lf) >> 16);
}
// returns lane(v ^ 8), via DPP row_ror:8 (xor-8 == ror-8 within 16-lane rows)
__device__ __forceinline__ float dpp8(float v) {
  return __int_as_float(__builtin_amdgcn_update_dpp(0, __float_as_int(v), 0x128, 0xF, 0xF, true));
}
__device__ __forceinline__ float rcp_f(float v)  { return __builtin_amdgcn_rcpf(v); }
__device__ __forceinline__ float sigm_f(float v) { return rcp_f(1.0f + __expf(-v)); }
__device__ __forceinline__ float tanh_f(float v) { return 1.0f - 2.0f * rcp_f(1.0f + __expf(2.0f * v)); }

// cumulative per-step flag target: step s completed by all 7 group waves
// when flg[slot s&7] >= 7*((s>>3)+1). s<0 -> 0 (trivially satisfied).
__device__ __forceinline__ int ftgt(int s) { return (s < 0) ? 0 : 7 * ((s >> 3) + 1); }

__device__ __forceinline__ void wait_flag(const volatile int* vf, int tgt) {
  if (tgt <= 0) return;
  if (*vf < tgt) {
    int guard = 1 << 13;                 // bailout: wrong answer beats a hang
    do { __builtin_amdgcn_s_sleep(1); } while (*vf < tgt && --guard);
  }
  asm volatile("" ::: "memory");         // no hoisting reads above this point
}

__global__ __launch_bounds__(NTH, 4)
void lstm_mfma14(const float* __restrict__ x,
                 const float* __restrict__ w_ih0, const float* __restrict__ w_hh0,
                 const float* __restrict__ b_ih0, const float* __restrict__ b_hh0,
                 const float* __restrict__ w_ih1, const float* __restrict__ w_hh1,
                 const float* __restrict__ b_ih1, const float* __restrict__ b_hh1,
                 const float* __restrict__ fc1_w, const float* __restrict__ fc1_b,
                 const float* __restrict__ fc2_w, const float* __restrict__ fc2_b,
                 float* __restrict__ out)
{
  // BARRIER-FREE producer/consumer, round 2.
  // r6 failed because the depth-2 h0 ring pinned L0 to "2 ahead" -> every L0
  // step blocked on L1's signal (lockstep + handoff latency). Fixes:
  //   (1) h0 ring depth 4 -> lag window [0,4]; natural lag ~1-2 sits inside ->
  //       steady state has ZERO poll-waits in either group (true decoupling).
  //   (2) L0's ring-guard wait (C1[t-4]) moved to just before the h0 write,
  //       where it is 4 steps stale; flag reads issued early & paired so the
  //       ~150cy LDS check latency overlaps other work.
  // Sync invariants: L0(t) waits C0[t-1] (intra-group, h0(t-1) ready) and
  // C1[t-4] (ring guard, before write). L1(s) waits C0[s] (h0(s) ready) and
  // C1[s-1] (intra-group, h1(s-1) ready; also guards depth-2 h1 ring).
  // Wait-graph acyclic. Numerics verbatim r6 (passed, absmax 4.88e-4).
  __shared__ __align__(16) short hbufS[6 * 1024];     // 12 KiB: h0 slots 0-3, h1 slots 0-1
  __shared__ __align__(16) short xfS[T_LEN * 128];    // 128 KiB: x fragments
  __shared__ __align__(16) float x8S[T_LEN * BG];     //  16 KiB: x[8]
  __shared__ float sF[BG * H];
  __shared__ float sY[BG * 28];
  __shared__ int   flg[16];                           // [0..7]=C0, [8..15]=C1

  const int tid  = threadIdx.x;
  const int lane = tid & 63;
  const int w    = tid >> 6;
  const int c16  = lane & 15;
  const int quad = lane >> 4;

  const int  grp  = (w >= 7);            // 0 = L0 group, 1 = L1 group
  const int  wg   = grp ? (w - 7) : w;   // 0..6 within group
  const bool selB = (c16 >= 8);          // lane's act item: stripe A or B
  const int  b    = lane & 7;
  const int  sA   = 2 * wg, sB = 2 * wg + 1;
  const int  j_sel = 4 * (selB ? sB : sA) + quad;     // this lane's h element j

  for (int i = tid; i < 3072; i += NTH) ((int*)hbufS)[i] = 0;
  if (tid < 16) flg[tid] = 0;

  // h store offset within a 1024-short slot (fragment-linear [64 rows][16 cols])
  const int kk   = j_sel & 31;
  const int offE = (j_sel >> 5) * 512 + ((kk >> 3) * 16 + b) * 8 + (kk & 7);

  // ---- x prefill: all 512 timesteps into LDS (fragment layout + x8 plane) ----
  for (int item = tid; item < T_LEN * BG; item += NTH) {
    const int t  = item & (T_LEN - 1);
    const int bb = item >> 9;
    const float* xr = x + ((size_t)(blockIdx.x * BG + bb) * T_LEN + t) * IN0;
    union { short s[8]; bfrag v; } hi, lo;
    #pragma unroll
    for (int q = 0; q < 8; ++q) split_bf16t(xr[q], hi.s[q], lo.s[q]);
    *(bfrag*)((char*)xfS + (size_t)t * 256 + bb * 16)       = hi.v;
    *(bfrag*)((char*)xfS + (size_t)t * 256 + (bb + 8) * 16) = lo.v;
    x8S[t * 8 + bb] = xr[8];
  }

  const char* const ldsb = (const char*)hbufS;
  const char* const xfb  = (const char*)xfS;
  const ffrag zerof = { 0.f, 0.f, 0.f, 0.f };
  const int incU1 = (quad == 3) ? 1024 : 0;   // x-frag advance per 4 steps
  float cst = 0.f;

  __syncthreads();                       // zeros + x prefill + flags visible

#define SIGNAL(IDX8, STEP)                                                      \
  asm volatile("s_waitcnt lgkmcnt(0)" ::: "memory");                            \
  if (lane == 0) atomicAdd(&flg[(IDX8) + ((STEP) & 7)], 1);

  if (!grp) {
    // ================= L0 group =================
    bfrag B0hA[2], B0lA[2], B0hB[2], B0lB[2];
#define LOADW0(SUF, SIDX)                                                       \
    {                                                                           \
      const int np_ = 16 * (SIDX) + c16;                                        \
      const int wrow_ = (np_ & 3) * H + (np_ >> 2);                             \
      _Pragma("unroll")                                                         \
      for (int s = 0; s < 2; ++s) {                                             \
        union { short sh[8]; bfrag v; } ah, al;                                 \
        _Pragma("unroll")                                                       \
        for (int jj = 0; jj < 8; ++jj) {                                        \
          const int k = 32 * s + quad * 8 + jj;                                 \
          const float w0 = (k < H) ? w_hh0[wrow_ * H + k]                       \
                                   : w_ih0[wrow_ * IN0 + (k - 56)];             \
          split_bf16(w0, ah.sh[jj], al.sh[jj]);                                 \
        }                                                                       \
        B0h##SUF[s] = ah.v; B0l##SUF[s] = al.v;                                 \
      }                                                                         \
    }
    LOADW0(A, sA)
    LOADW0(B, sB)
#undef LOADW0

    ffrag bias0A, bias0B;
    #pragma unroll
    for (int r = 0; r < 4; ++r) {
      const int jA = 4 * sA + quad, jB = 4 * sB + quad;
      bias0A[r] = (c16 < 8) ? (b_ih0[r * H + jA] + b_hh0[r * H + jA]) : 0.0f;
      bias0B[r] = (c16 < 8) ? (b_ih0[r * H + jB] + b_hh0[r * H + jB]) : 0.0f;
    }
    float wx8s[4];
    #pragma unroll
    for (int r = 0; r < 4; ++r)
      wx8s[r] = w_ih0[(r * H + j_sel) * IN0 + 8];

    // read slot (t-1)&3; for t ≡ P (mod 4) -> slot (P+3)&3. write slot P.
    const char* const pU0_0 = ldsb + 3 * 2048 + lane * 16;
    const char* const pU0_1 = ldsb + 0 * 2048 + lane * 16;
    const char* const pU0_2 = ldsb + 1 * 2048 + lane * 16;
    const char* const pU0_3 = ldsb + 2 * 2048 + lane * 16;
    const char* pU1_0 = (quad == 3) ? (xfb + 0 * 256 + c16 * 16) : (pU0_0 + 1024);
    const char* pU1_1 = (quad == 3) ? (xfb + 1 * 256 + c16 * 16) : (pU0_1 + 1024);
    const char* pU1_2 = (quad == 3) ? (xfb + 2 * 256 + c16 * 16) : (pU0_2 + 1024);
    const char* pU1_3 = (quad == 3) ? (xfb + 3 * 256 + c16 * 16) : (pU0_3 + 1024);
    const char* px8_0 = (const char*)x8S + 0 * 32 + b * 4;
    const char* px8_1 = (const char*)x8S + 1 * 32 + b * 4;
    const char* px8_2 = (const char*)x8S + 2 * 32 + b * 4;
    const char* px8_3 = (const char*)x8S + 3 * 32 + b * 4;
    short* const hw_0 = hbufS + 0 * 1024 + offE;
    short* const hw_1 = hbufS + 1 * 1024 + offE;
    short* const hw_2 = hbufS + 2 * 1024 + offE;
    short* const hw_3 = hbufS + 3 * 1024 + offE;

#define STEP0(P, TT)                                                            \
    {                                                                           \
      const float x8v = *(const float*)px8_##P;                                 \
      const volatile int* c0p_ = (const volatile int*)&flg[((TT) - 1) & 7];     \
      const volatile int* c1p_ = (const volatile int*)&flg[8 + (((TT) - 4) & 7)]; \
      const int v0_ = *c0p_;                /* both flag reads in flight */     \
      const int v1_ = *c1p_;                                                    \
      const int t0_ = ftgt((TT) - 1), t1_ = ftgt((TT) - 4);                     \
      if (v0_ < t0_) wait_flag(c0p_, t0_);                                      \
      asm volatile("" ::: "memory");                                            \
      const bfrag U0 = *(const bfrag*)pU0_##P;                                  \
      const bfrag U1 = *(const bfrag*)pU1_##P;                                  \
      __builtin_amdgcn_s_setprio(1);                                            \
      ffrag aA = MFMA(B0hA[0], U0, bias0A);                                     \
      ffrag bA = MFMA(B0lA[0], U0, zerof);                                      \
      aA = MFMA(B0hA[1], U1, aA);                                               \
      bA = MFMA(B0lA[1], U1, bA);                                               \
      ffrag aB = MFMA(B0hB[0], U0, bias0B);                                     \
      ffrag bB = MFMA(B0lB[0], U0, zerof);                                      \
      aB = MFMA(B0hB[1], U1, aB);                                               \
      bB = MFMA(B0lB[1], U1, bB);                                               \
      __builtin_amdgcn_s_setprio(0);                                            \
      float sv[4];                                                              \
      _Pragma("unroll")                                                         \
      for (int r = 0; r < 4; ++r) {                                             \
        const float da = aA[r] + bA[r];                                         \
        const float db = aB[r] + bB[r];                                         \
        const float uu = selB ? db : da;                                        \
        const float vv = selB ? da : db;                                        \
        sv[r] = uu + dpp8(vv);                                                  \
      }                                                                         \
      const float gi = fmaf(wx8s[0], x8v, sv[0]);                               \
      const float gf = fmaf(wx8s[1], x8v, sv[1]);                               \
      const float gg = fmaf(wx8s[2], x8v, sv[2]);                               \
      const float go = fmaf(wx8s[3], x8v, sv[3]);                               \
      const float iv = sigm_f(gi), fv = sigm_f(gf);                             \
      const float gv = tanh_f(gg), ov = sigm_f(go);                             \
      cst = fmaf(fv, cst, iv * gv);                                             \
      const float hv = ov * tanh_f(cst);                                        \
      short hs, hl; split_bf16t(hv, hs, hl);                                    \
      if (v1_ < t1_) wait_flag(c1p_, t1_);  /* ring guard, 4 steps stale */     \
      asm volatile("" ::: "memory");                                            \
      hw_##P[0] = hs; hw_##P[64] = hl;                                          \
      SIGNAL(0, TT)                                                             \
    }

    for (int t = 0; t < T_LEN; t += 4) {
      STEP0(0, t)
      STEP0(1, t + 1)
      STEP0(2, t + 2)
      STEP0(3, t + 3)
      pU1_0 += incU1; pU1_1 += incU1; pU1_2 += incU1; pU1_3 += incU1;
      px8_0 += 128;   px8_1 += 128;   px8_2 += 128;   px8_3 += 128;
    }
#undef STEP0
  } else {
    // ================= L1 group =================
    bfrag BuhA[2], BhhA[2], BuhB[2], BhhB[2];
#define LOADW1(SUF, SIDX)                                                       \
    {                                                                           \
      const int np_ = 16 * (SIDX) + c16;                                        \
      const int wrow_ = (np_ & 3) * H + (np_ >> 2);                             \
      _Pragma("unroll")                                                         \
      for (int s = 0; s < 2; ++s) {                                             \
        union { short sh[8]; bfrag v; } au, ah;                                 \
        _Pragma("unroll")                                                       \
        for (int jj = 0; jj < 8; ++jj) {                                        \
          const int k = 32 * s + quad * 8 + jj;                                 \
          const float wu = (k < H) ? w_ih1[wrow_ * H + k] : 0.0f;               \
          const float wh = (k < H) ? w_hh1[wrow_ * H + k] : 0.0f;               \
          short dum;                                                            \
          split_bf16(wu, au.sh[jj], dum);   /* RNE hi only */                   \
          split_bf16(wh, ah.sh[jj], dum);                                       \
        }                                                                       \
        Buh##SUF[s] = au.v; Bhh##SUF[s] = ah.v;                                 \
      }                                                                         \
    }
    LOADW1(A, sA)
    LOADW1(B, sB)
#undef LOADW1

    ffrag bias1A, bias1B;
    #pragma unroll
    for (int r = 0; r < 4; ++r) {
      const int jA = 4 * sA + quad, jB = 4 * sB + quad;
      bias1A[r] = (c16 < 8) ? (b_ih1[r * H + jA] + b_hh1[r * H + jA]) : 0.0f;
      bias1B[r] = (c16 < 8) ? (b_ih1[r * H + jB] + b_hh1[r * H + jB]) : 0.0f;
    }

    // U = h0(s) slot s&3 = P; H = h1(s-1) slot (s-1)&1 = (P+1)&1; write slot P&1
    const char* const qU0_0 = ldsb + 0 * 2048 + lane * 16;
    const char* const qU0_1 = ldsb + 1 * 2048 + lane * 16;
    const char* const qU0_2 = ldsb + 2 * 2048 + lane * 16;
    const char* const qU0_3 = ldsb + 3 * 2048 + lane * 16;
    const char* qU1_0 = (quad == 3) ? (xfb + 0 * 256 + c16 * 16) : (qU0_0 + 1024);
    const char* qU1_1 = (quad == 3) ? (xfb + 1 * 256 + c16 * 16) : (qU0_1 + 1024);
    const char* qU1_2 = (quad == 3) ? (xfb + 2 * 256 + c16 * 16) : (qU0_2 + 1024);
    const char* qU1_3 = (quad == 3) ? (xfb + 3 * 256 + c16 * 16) : (qU0_3 + 1024);
    const char* const qH0_0 = ldsb + 8192 + 2048 + lane * 16;   // h1 slot 1
    const char* const qH0_1 = ldsb + 8192 +        lane * 16;   // h1 slot 0
    const char* const qH0_2 = qH0_0;
    const char* const qH0_3 = qH0_1;
    short* const qw_0 = hbufS + 4096 + 0 * 1024 + offE;
    short* const qw_1 = hbufS + 4096 + 1 * 1024 + offE;
    short* const qw_2 = qw_0;
    short* const qw_3 = qw_1;

#define STEP1(P, SS, LAST)                                                      \
    {                                                                           \
      const volatile int* f0_ = (const volatile int*)&flg[(SS) & 7];            \
      const volatile int* f1_ = (const volatile int*)&flg[8 + (((SS) - 1) & 7)]; \
      const int v0_ = *f0_;                 /* both flag reads in flight */     \
      const int v1_ = *f1_;                                                     \
      const int t0_ = ftgt(SS), t1_ = ftgt((SS) - 1);                           \
      if (v0_ < t0_) wait_flag(f0_, t0_);                                       \
      if (v1_ < t1_) wait_flag(f1_, t1_);                                       \
      asm volatile("" ::: "memory");                                            \
      const bfrag U0 = *(const bfrag*)qU0_##P;                                  \
      const bfrag U1 = *(const bfrag*)qU1_##P;                                  \
      const bfrag H0 = *(const bfrag*)qH0_##P;                                  \
      const bfrag H1 = *(const bfrag*)(qH0_##P + 1024);                         \
      __builtin_amdgcn_s_setprio(1);                                            \
      ffrag hA = MFMA(BhhA[0], H0, bias1A);                                     \
      hA = MFMA(BhhA[1], H1, hA);                                               \
      hA = MFMA(BuhA[0], U0, hA);                                               \
      hA = MFMA(BuhA[1], U1, hA);                                               \
      ffrag hBv = MFMA(BhhB[0], H0, bias1B);                                    \
      hBv = MFMA(BhhB[1], H1, hBv);                                             \
      hBv = MFMA(BuhB[0], U0, hBv);                                             \
      hBv = MFMA(BuhB[1], U1, hBv);                                             \
      __builtin_amdgcn_s_setprio(0);                                            \
      float sv[4];                                                              \
      _Pragma("unroll")                                                         \
      for (int r = 0; r < 4; ++r) {                                             \
        const float uu = selB ? hBv[r] : hA[r];                                 \
        const float vv = selB ? hA[r] : hBv[r];                                 \
        sv[r] = uu + dpp8(vv);                                                  \
      }                                                                         \
      const float iv = sigm_f(sv[0]), fv = sigm_f(sv[1]);                       \
      const float gv = tanh_f(sv[2]), ov = sigm_f(sv[3]);                       \
      cst = fmaf(fv, cst, iv * gv);                                             \
      const float hv = ov * tanh_f(cst);                                        \
      if (!(LAST)) {                                                            \
        short hs, hl; split_bf16t(hv, hs, hl);                                  \
        qw_##P[0] = hs; qw_##P[64] = hl;                                        \
        SIGNAL(8, SS)                                                           \
      } else {                                                                  \
        sF[b * H + j_sel] = hv;                                                 \
      }                                                                         \
    }

    for (int s = 0; s < T_LEN - 4; s += 4) {
      STEP1(0, s, 0)
      STEP1(1, s + 1, 0)
      STEP1(2, s + 2, 0)
      STEP1(3, s + 3, 0)
      qU1_0 += incU1; qU1_1 += incU1; qU1_2 += incU1; qU1_3 += incU1;
    }
    STEP1(0, T_LEN - 4, 0)
    STEP1(1, T_LEN - 3, 0)
    STEP1(2, T_LEN - 2, 0)
    STEP1(3, T_LEN - 1, 1)
#undef STEP1
  }
#undef SIGNAL

  __syncthreads();

  // ---- FC head on final h1 ----
  if (tid < 28 * BG) {
    const int m  = tid >> 3;
    const int bb = tid & 7;
    float acc = fc1_b[m];
    const float4* w4 = (const float4*)(fc1_w + m * H);
    const float4* h4 = (const float4*)(sF + bb * H);
    #pragma unroll
    for (int qq = 0; qq < H / 4; ++qq) {
      const float4 wv4 = w4[qq], hv4 = h4[qq];
      acc = fmaf(wv4.x, hv4.x, acc);
      acc = fmaf(wv4.y, hv4.y, acc);
      acc = fmaf(wv4.z, hv4.z, acc);
      acc = fmaf(wv4.w, hv4.w, acc);
    }
    sY[bb * 28 + m] = fmaxf(acc, 0.0f);
  }
  __syncthreads();
  if (tid < BG) {
    float acc = fc2_b[0];
    #pragma unroll
    for (int m = 0; m < 28; ++m)
      acc = fmaf(fc2_w[m], sY[tid * 28 + m], acc);
    out[blockIdx.x * BG + tid] = acc;
  }
}

extern "C" void kernel_launch(void* const* d_in, const int* in_sizes, int n_in,
                              void* d_out, int out_size, void* d_ws, size_t ws_size,
                              hipStream_t stream)
{
  const float* x     = (const float*)d_in[0];
  const float* w_ih0 = (const float*)d_in[1];
  const float* w_hh0 = (const float*)d_in[2];
  const float* b_ih0 = (const float*)d_in[3];
  const float* b_hh0 = (const float*)d_in[4];
  const float* w_ih1 = (const float*)d_in[5];
  const float* w_hh1 = (const float*)d_in[6];
  const float* b_ih1 = (const float*)d_in[7];
  const float* b_hh1 = (const float*)d_in[8];
  const float* fc1_w = (const float*)d_in[9];
  const float* fc1_b = (const float*)d_in[10];
  const float* fc2_w = (const float*)d_in[11];
  const float* fc2_b = (const float*)d_in[12];
  float* out = (float*)d_out;

  lstm_mfma14<<<NBLK, NTH, 0, stream>>>(
      x, w_ih0, w_hh0, b_ih0, b_hh0, w_ih1, w_hh1, b_ih1, b_hh1,
      fc1_w, fc1_b, fc2_w, fc2_b, out);
}

// Round 8
// 431.928 us; speedup vs baseline: 1.1461x; 1.1096x over previous
//
#include <hip/hip_runtime.h>
#include <stdint.h>

#define T_LEN 512
#define IN0   9
#define H     56
#define BG    8
#define NW    14
#define NTH   (NW * 64)        // 896 threads, 14 waves
#define NBLK  256

typedef __attribute__((ext_vector_type(8))) short bfrag;   // 8 bf16
typedef __attribute__((ext_vector_type(4))) float ffrag;   // 4 fp32

#define MFMA(a,b,c) __builtin_amdgcn_mfma_f32_16x16x32_bf16((a),(b),(c),0,0,0)

__device__ __forceinline__ uint32_t bf16hi(float x) {
  uint32_t u = __float_as_uint(x);
  return (u + 0x7FFFu + ((u >> 16) & 1u)) & 0xFFFF0000u;
}
// RNE both halves (weights, init-time only)
__device__ __forceinline__ void split_bf16(float x, short& hs, short& ls) {
  uint32_t hb = bf16hi(x);
  float lf = x - __uint_as_float(hb);
  hs = (short)(hb >> 16);
  ls = (short)(bf16hi(lf) >> 16);
}
// RNE hi, truncated lo (loop-time)
__device__ __forceinline__ void split_bf16t(float x, short& hs, short& ls) {
  uint32_t hb = bf16hi(x);
  float lf = x - __uint_as_float(hb);
  hs = (short)(hb >> 16);
  ls = (short)(__float_as_uint(lf) >> 16);
}
// returns lane(v ^ 8), via DPP row_ror:8 (xor-8 == ror-8 within 16-lane rows)
__device__ __forceinline__ float dpp8(float v) {
  return __int_as_float(__builtin_amdgcn_update_dpp(0, __float_as_int(v), 0x128, 0xF, 0xF, true));
}
__device__ __forceinline__ float rcp_f(float v)  { return __builtin_amdgcn_rcpf(v); }
__device__ __forceinline__ float sigm_f(float v) { return rcp_f(1.0f + __expf(-v)); }
__device__ __forceinline__ float tanh_f(float v) { return 1.0f - 2.0f * rcp_f(1.0f + __expf(2.0f * v)); }

__global__ __launch_bounds__(NTH, 4)
void lstm_mfma15(const float* __restrict__ x,
                 const float* __restrict__ w_ih0, const float* __restrict__ w_hh0,
                 const float* __restrict__ b_ih0, const float* __restrict__ b_hh0,
                 const float* __restrict__ w_ih1, const float* __restrict__ w_hh1,
                 const float* __restrict__ b_ih1, const float* __restrict__ b_hh1,
                 const float* __restrict__ fc1_w, const float* __restrict__ fc1_b,
                 const float* __restrict__ fc2_w, const float* __restrict__ fc2_b,
                 float* __restrict__ out)
{
  // Lockstep structure (best measured: 402us rocprof). x fully LDS-resident;
  // zero global memory in the main loop. NEW: per-wave read/chain ROTATION —
  // even waves read U0,U1,H0,H1 and compute the a0-chain first; odd waves read
  // H0,H1,U0,U1 and compute the aH-chain first. All 14 waves' region-start LDS
  // burst (~56KB, ~450cy drain at 128B/cy) previously made every wave wait for
  // the SAME first operand; rotation lets half the waves start MFMAs as soon
  // as their first-issued read lands. Chain-internal order unchanged ->
  // bitwise-identical numerics. setprio removed (proven flat r2 vs r3).
  __shared__ __align__(16) short hbufS[4 * 1024];     //  8 KiB: h ring (4 regions)
  __shared__ __align__(16) short xfS[T_LEN * 128];    // 128 KiB: x fragments
  __shared__ __align__(16) float x8S[T_LEN * BG];     //  16 KiB: x[8]
  __shared__ float sF[BG * H];
  __shared__ float sY[BG * 28];

  const int tid  = threadIdx.x;
  const int lane = tid & 63;
  const int w    = tid >> 6;
  const int c16  = lane & 15;
  const int quad = lane >> 4;
  const bool wodd = (w & 1);

  const int np   = 16 * w + c16;       // n' = 4j+g (A-operand M index)
  const int jb   = np >> 2, gb = np & 3;
  const int wrow = gb * H + jb;

  for (int i = tid; i < 2048; i += NTH) ((int*)hbufS)[i] = 0;

  // ---- A-fragments (weights): A[m=c16][k=quad*8+jj] ----
  bfrag B0h[2], B0l[2], Buh[2], Bhh[2];
  #pragma unroll
  for (int s = 0; s < 2; ++s) {
    union { short sh[8]; bfrag v; } a0h, a0l, auh, ahh;
    #pragma unroll
    for (int jj = 0; jj < 8; ++jj) {
      const int k = 32 * s + quad * 8 + jj;
      const float w0 = (k < H) ? w_hh0[wrow * H + k] : w_ih0[wrow * IN0 + (k - 56)];
      const float wu = (k < H) ? w_ih1[wrow * H + k] : 0.0f;
      const float wh = (k < H) ? w_hh1[wrow * H + k] : 0.0f;
      split_bf16(w0, a0h.sh[jj], a0l.sh[jj]);
      short dum;
      split_bf16(wu, auh.sh[jj], dum);   // RNE hi only
      split_bf16(wh, ahh.sh[jj], dum);
    }
    B0h[s] = a0h.v; B0l[s] = a0l.v;
    Buh[s] = auh.v; Bhh[s] = ahh.v;
  }

  // D rows m = 4*quad + r -> gate g=r of j4 = 4w+quad. Bias rides C on hi cols.
  const int j4 = 4 * w + quad;
  ffrag bias0f, bias1f;
  #pragma unroll
  for (int r = 0; r < 4; ++r) {
    const float v0 = b_ih0[r * H + j4] + b_hh0[r * H + j4];
    const float v1 = b_ih1[r * H + j4] + b_hh1[r * H + j4];
    bias0f[r] = (c16 < 8) ? v0 : 0.0f;
    bias1f[r] = (c16 < 8) ? v1 : 0.0f;
  }
  const ffrag zerof = { 0.f, 0.f, 0.f, 0.f };

  // act identity: lay=0 (c16<8) -> layer1 element (b, j4); lay=1 -> layer0
  const int lay = (lane >> 3) & 1;
  const int b   = lane & 7;
  float wx8a[4];
  #pragma unroll
  for (int r = 0; r < 4; ++r)
    wx8a[r] = lay ? w_ih0[(r * H + j4) * IN0 + 8] : 0.0f;

  // h store offsets (shorts, relative to hbufS)
  const int kk   = j4 & 31;
  const int offE = (j4 >> 5) * 512 + ((kk >> 3) * 16 + b) * 8 + (kk & 7);
  short* const hp0 = hbufS + (lay ? 0 : 3 * 1024) + offE;
  short* const hp1 = hbufS + (lay ? 1 * 1024 : 2 * 1024) + offE;

  // ---- x prefill: all 512 timesteps into LDS (fragment layout + x8 plane) ----
  for (int item = tid; item < T_LEN * BG; item += NTH) {
    const int t  = item & (T_LEN - 1);
    const int bb = item >> 9;
    const float* xr = x + ((size_t)(blockIdx.x * BG + bb) * T_LEN + t) * IN0;
    union { short s[8]; bfrag v; } hi, lo;
    #pragma unroll
    for (int q = 0; q < 8; ++q) split_bf16t(xr[q], hi.s[q], lo.s[q]);
    *(bfrag*)((char*)xfS + (size_t)t * 256 + bb * 16)       = hi.v;
    *(bfrag*)((char*)xfS + (size_t)t * 256 + (bb + 8) * 16) = lo.v;
    x8S[t * 8 + bb] = xr[8];
  }

  // ---- per-lane LDS read pointers ----
  const char* const hB = (const char*)hbufS;
  const char* const pU0_0 = hB + 2048 + lane * 16;   // sB[1] k0..31
  const char* const pU0_1 = hB +        lane * 16;   // sB[0]
  const char* const pH0_0 = hB + 4096 + lane * 16;   // sB[2]
  const char* const pH1_0 = hB + 5120 + lane * 16;
  const char* const pH0_1 = hB + 6144 + lane * 16;   // sB[3]
  const char* const pH1_1 = hB + 7168 + lane * 16;
  // U1: quads 0-2 read h rows k32..55 from ring; quad 3 reads x(t) plane
  const char* pU1_0 = (quad == 3) ? ((const char*)xfS + 256 * 1 + c16 * 16)
                                  : (hB + 3072 + lane * 16);
  const char* pU1_1 = (quad == 3) ? ((const char*)xfS + 256 * 2 + c16 * 16)
                                  : (hB + 1024 + lane * 16);
  const char* px8_0 = (const char*)x8S + 32 * 1 + b * 4;
  const char* px8_1 = (const char*)x8S + 32 * 2 + b * 4;
  const int incU1 = (quad == 3) ? 512 : 0;

  float cst = 0.f;                     // lay0: c1, lay1: c0
  __syncthreads();                     // zeros + x prefill visible

  // ---- prologue: L0(t=0); U0 and h-part of U1 are zeros, x(0) from xfS ----
  {
    const bfrag U0 = *(const bfrag*)(hB + lane * 16);                  // zeros
    const char* pU1p = (quad == 3) ? ((const char*)xfS + c16 * 16)
                                   : (hB + 1024 + lane * 16);          // zeros
    const bfrag U1 = *(const bfrag*)pU1p;
    const float x8v = x8S[b];
    ffrag a0 = MFMA(B0h[0], U0, bias0f);
    a0 = MFMA(B0h[1], U1, a0);
    a0 = MFMA(B0l[0], U0, a0);
    a0 = MFMA(B0l[1], U1, a0);
    float s0[4];
    #pragma unroll
    for (int r = 0; r < 4; ++r) s0[r] = a0[r] + dpp8(a0[r]);
    if (lay) {
      const float gi = fmaf(wx8a[0], x8v, s0[0]);
      const float gf = fmaf(wx8a[1], x8v, s0[1]);
      const float gg = fmaf(wx8a[2], x8v, s0[2]);
      const float go = fmaf(wx8a[3], x8v, s0[3]);
      const float iv = sigm_f(gi), fv = sigm_f(gf);
      const float gv = tanh_f(gg), ov = sigm_f(go);
      cst = fmaf(fv, cst, iv * gv);
      const float hv = ov * tanh_f(cst);
      short hs, hl; split_bf16t(hv, hs, hl);
      hp1[0] = hs; hp1[64] = hl;       // h0(0) -> sB[1]
    }
    __syncthreads();
  }

#define REGION(RR, L0PART, LASTR, X8V)                                          \
  {                                                                             \
    bfrag U0, U1, H0, H1;                                                       \
    ffrag a0a, a0b, aH;                                                         \
    if (!wodd) {                                                                \
      /* even waves: U first, a0-chain first */                                 \
      U0 = *(const bfrag*)pU0_##RR;                                             \
      U1 = *(const bfrag*)pU1_##RR;                                             \
      H0 = *(const bfrag*)pH0_##RR;                                             \
      H1 = *(const bfrag*)pH1_##RR;                                             \
      if (L0PART) {                                                             \
        a0a = MFMA(B0h[0], U0, bias0f);                                         \
        a0b = MFMA(B0l[0], U0, zerof);                                          \
        a0a = MFMA(B0h[1], U1, a0a);                                            \
        a0b = MFMA(B0l[1], U1, a0b);                                            \
      }                                                                         \
      aH = MFMA(Bhh[0], H0, bias1f);                                            \
      aH = MFMA(Bhh[1], H1, aH);                                                \
      aH = MFMA(Buh[0], U0, aH);                                                \
      aH = MFMA(Buh[1], U1, aH);                                                \
    } else {                                                                    \
      /* odd waves: H first, aH-chain first (chain-internal order identical) */ \
      H0 = *(const bfrag*)pH0_##RR;                                             \
      H1 = *(const bfrag*)pH1_##RR;                                             \
      U0 = *(const bfrag*)pU0_##RR;                                             \
      U1 = *(const bfrag*)pU1_##RR;                                             \
      aH = MFMA(Bhh[0], H0, bias1f);                                            \
      aH = MFMA(Bhh[1], H1, aH);                                                \
      aH = MFMA(Buh[0], U0, aH);                                                \
      aH = MFMA(Buh[1], U1, aH);                                                \
      if (L0PART) {                                                             \
        a0a = MFMA(B0h[0], U0, bias0f);                                         \
        a0b = MFMA(B0l[0], U0, zerof);                                          \
        a0a = MFMA(B0h[1], U1, a0a);                                            \
        a0b = MFMA(B0l[1], U1, a0b);                                            \
      }                                                                         \
    }                                                                           \
    if (!LASTR) {                                                               \
      /* lane^8 partner has opposite lay: one dpp-add gives each lane its sum */\
      float sv[4];                                                              \
      _Pragma("unroll")                                                         \
      for (int r = 0; r < 4; ++r) {                                             \
        const float t0 = a0a[r] + a0b[r];                                       \
        const float uu = lay ? t0 : aH[r];                                      \
        const float vv = lay ? aH[r] : t0;                                      \
        sv[r] = uu + dpp8(vv);                                                  \
      }                                                                         \
      const float gi = fmaf(wx8a[0], (X8V), sv[0]);                             \
      const float gf = fmaf(wx8a[1], (X8V), sv[1]);                             \
      const float gg = fmaf(wx8a[2], (X8V), sv[2]);                             \
      const float go = fmaf(wx8a[3], (X8V), sv[3]);                             \
      const float iv = sigm_f(gi), fv = sigm_f(gf);                             \
      const float gv = tanh_f(gg), ov = sigm_f(go);                             \
      cst = fmaf(fv, cst, iv * gv);                                             \
      const float hv = ov * tanh_f(cst);                                        \
      short hs, hl; split_bf16t(hv, hs, hl);                                    \
      short* hb2 = (RR == 0) ? hp0 : hp1;                                       \
      hb2[0] = hs; hb2[64] = hl;                                                \
    } else {                                                                    \
      float s1[4];                                                              \
      _Pragma("unroll")                                                         \
      for (int r = 0; r < 4; ++r) s1[r] = aH[r] + dpp8(aH[r]);                  \
      if (lay == 0) {                                                           \
        const float iv = sigm_f(s1[0]), fv = sigm_f(s1[1]);                     \
        const float gv = tanh_f(s1[2]), ov = sigm_f(s1[3]);                     \
        cst = fmaf(fv, cst, iv * gv);                                           \
        sF[b * H + j4] = ov * tanh_f(cst);                                      \
      }                                                                         \
    }                                                                           \
    __syncthreads();                                                            \
  }

  // main: 255 iters x 2 regions (t=1..510), then t=511, then L1-only tail
  for (int it = 0; it < 255; ++it) {
    // hoist both x8 loads: stable data, full region to cover latency
    const float x8v0 = *(const float*)px8_0;
    const float x8v1 = *(const float*)px8_1;
    REGION(0, 1, 0, x8v0)
    REGION(1, 1, 0, x8v1)
    pU1_0 += incU1; pU1_1 += incU1;
    px8_0 += 64;    px8_1 += 64;
  }
  {
    const float x8v0 = *(const float*)px8_0;
    REGION(0, 1, 0, x8v0)
  }
  // pU1_1 would be one timestep past xfS (t=512): pull it back in-bounds.
  // Data is irrelevant (Buh rows k>=56 are zero) but OOB garbage risks 0*Inf=NaN.
  pU1_1 -= incU1;
  REGION(1, 0, 1, 0.0f)
#undef REGION

  // ---- FC head on final h1 ----
  if (tid < 28 * BG) {
    const int m  = tid >> 3;
    const int bb = tid & 7;
    float acc = fc1_b[m];
    const float4* w4 = (const float4*)(fc1_w + m * H);
    const float4* h4 = (const float4*)(sF + bb * H);
    #pragma unroll
    for (int qq = 0; qq < H / 4; ++qq) {
      const float4 wv4 = w4[qq], hv4 = h4[qq];
      acc = fmaf(wv4.x, hv4.x, acc);
      acc = fmaf(wv4.y, hv4.y, acc);
      acc = fmaf(wv4.z, hv4.z, acc);
      acc = fmaf(wv4.w, hv4.w, acc);
    }
    sY[bb * 28 + m] = fmaxf(acc, 0.0f);
  }
  __syncthreads();
  if (tid < BG) {
    float acc = fc2_b[0];
    #pragma unroll
    for (int m = 0; m < 28; ++m)
      acc = fmaf(fc2_w[m], sY[tid * 28 + m], acc);
    out[blockIdx.x * BG + tid] = acc;
  }
}

extern "C" void kernel_launch(void* const* d_in, const int* in_sizes, int n_in,
                              void* d_out, int out_size, void* d_ws, size_t ws_size,
                              hipStream_t stream)
{
  const float* x     = (const float*)d_in[0];
  const float* w_ih0 = (const float*)d_in[1];
  const float* w_hh0 = (const float*)d_in[2];
  const float* b_ih0 = (const float*)d_in[3];
  const float* b_hh0 = (const float*)d_in[4];
  const float* w_ih1 = (const float*)d_in[5];
  const float* w_hh1 = (const float*)d_in[6];
  const float* b_ih1 = (const float*)d_in[7];
  const float* b_hh1 = (const float*)d_in[8];
  const float* fc1_w = (const float*)d_in[9];
  const float* fc1_b = (const float*)d_in[10];
  const float* fc2_w = (const float*)d_in[11];
  const float* fc2_b = (const float*)d_in[12];
  float* out = (float*)d_out;

  lstm_mfma15<<<NBLK, NTH, 0, stream>>>(
      x, w_ih0, w_hh0, b_ih0, b_hh0, w_ih1, w_hh1, b_ih1, b_hh1,
      fc1_w, fc1_b, fc2_w, fc2_b, out);
}